// Round 5
// baseline (349.911 us; speedup 1.0000x reference)
//
#include <hip/hip_runtime.h>

// LogitSelector: per-row top-100 (ascending), label position, miss→replace col 0.
// Reference: jax.lax.top_k (ties: lower index first), reversed; take_along_axis; argmax.
//
// Strategy: speculative-threshold filter (t=1.9 on N(0,1) -> ~193 candidates/row,
// always in [K, CAP]; bisection fallback for arbitrary data), candidates packed
// as 64-bit sort keys in LDS, exact O(C^2) rank computed via per-wave register
// tiles + readlane broadcast (VALU) instead of LDS broadcast reads -- the LDS
// pipe (shared by 8 resident blocks/CU) was the R4 bottleneck (~49k LDS ops/CU
// ~= 104us; now ~500).

#define NROWS 8192
#define NCOLS 6714
#define NC2   3357     // NCOLS/2 exact; rows are 8B-aligned (26856 % 8 == 0)
#define K     100
#define CAP   512
#define BLK   256

__device__ __forceinline__ unsigned int flip32(float v) {
    unsigned int b = __float_as_uint(v);
    return ((int)b < 0) ? ~b : (b | 0x80000000u);   // order-preserving for all floats
}
__device__ __forceinline__ float unflip32(unsigned int k) {
    unsigned int b = (k & 0x80000000u) ? (k ^ 0x80000000u) : ~k;
    return __uint_as_float(b);
}

__global__ __launch_bounds__(BLK) void logit_selector_kernel(
    const float* __restrict__ out_mat,
    const int*   __restrict__ labels,
    float*       __restrict__ new_out,   // [NROWS][K]
    float*       __restrict__ new_lab)   // [NROWS] written as float
{
    __shared__ unsigned long long ckey[CAP];   // 4096 B
    __shared__ unsigned int s_cnum;
    __shared__ int          s_lab;
    __shared__ int          s_has;

    const int row  = blockIdx.x;
    const int tid  = threadIdx.x;
    const int lane = tid & 63;
    const float*  __restrict__ rp  = out_mat + (size_t)row * NCOLS;
    const float2* __restrict__ rp2 = (const float2*)rp;

    if (tid == 0) { s_has = 0; s_lab = 0; }

    // --- Candidate collection with speculative threshold (+ bisection fallback).
    // Normal case: exactly one pass at t=1.9.
    float lo = -50.0f, hi = 50.0f;
    float t  = 1.9f;
    unsigned int cnt;
    for (int attempt = 0; ; ++attempt) {
        if (tid == 0) s_cnum = 0;
        __syncthreads();

        #pragma unroll 4
        for (int i = tid; i < NC2; i += BLK) {
            float2 v2 = rp2[i];
            if (v2.x > t) {
                unsigned int p = atomicAdd(&s_cnum, 1u);
                if (p < CAP)
                    ckey[p] = ((unsigned long long)flip32(v2.x) << 32)
                            | (unsigned int)~(unsigned int)(2 * i);
            }
            if (v2.y > t) {
                unsigned int p = atomicAdd(&s_cnum, 1u);
                if (p < CAP)
                    ckey[p] = ((unsigned long long)flip32(v2.y) << 32)
                            | (unsigned int)~(unsigned int)(2 * i + 1);
            }
        }
        __syncthreads();
        cnt = s_cnum;                       // uniform across block
        if ((cnt >= K && cnt <= CAP) || attempt >= 62) break;
        if (cnt < (unsigned int)K) hi = t; else lo = t;
        t = 0.5f * (lo + hi);
        __syncthreads();                    // protect next reset vs. cnt reads
    }

    const int C    = (int)min(cnt, (unsigned int)CAP);
    const int Cpad = (C + 63) & ~63;        // <= CAP

    // Zero-pad: key 0 beats nothing (all real keys have nonzero high word).
    for (int c = C + tid; c < Cpad; c += BLK) ckey[c] = 0ULL;
    __syncthreads();

    const int label = labels[row];

    // --- Exact ranking. rank(j) = #{c : key_c > key_j}; bijective onto [0,C).
    // rank k < K -> output column (K-1)-k (reference reverses top_k order).
    // Tile candidates into wave registers (1 ds_read_b64 / 64 candidates), then
    // broadcast via readlane (VALU). NOTE: tile loads must run with ALL lanes
    // active -- readlane ignores exec, so inactive lanes' regs would be garbage.
    for (int jbase = 0; jbase < C; jbase += BLK) {      // uniform trip count
        const int  j      = jbase + tid;
        const bool active = (j < C);
        const unsigned long long kj = active ? ckey[j] : 0ULL;
        int rank = 0;
        for (int cb = 0; cb < Cpad; cb += 64) {
            const unsigned long long kt = ckey[cb + lane];   // all lanes execute
            const unsigned int tlo = (unsigned int)kt;
            const unsigned int thi = (unsigned int)(kt >> 32);
            #pragma unroll
            for (int l = 0; l < 64; ++l) {
                const unsigned int clo = __builtin_amdgcn_readlane(tlo, l);
                const unsigned int chi = __builtin_amdgcn_readlane(thi, l);
                const unsigned long long kc =
                    ((unsigned long long)chi << 32) | clo;
                rank += (kc > kj);
            }
        }
        if (active && rank < K) {
            const int col = (K - 1) - rank;
            const float        vj = unflip32((unsigned int)(kj >> 32));
            const unsigned int ij = ~(unsigned int)kj;
            new_out[(size_t)row * K + col] = vj;
            if ((int)ij == label) { s_has = 1; s_lab = col; }
        }
    }
    __syncthreads();

    if (tid == 0) {
        int lab = s_lab;
        if (!s_has) {                       // label missed top-K: replace col 0
            new_out[(size_t)row * K] = rp[label];
            lab = 0;
        }
        new_lab[row] = (float)lab;
    }
}

extern "C" void kernel_launch(void* const* d_in, const int* in_sizes, int n_in,
                              void* d_out, int out_size, void* d_ws, size_t ws_size,
                              hipStream_t stream) {
    const float* out_mat = (const float*)d_in[0];
    const int*   labels  = (const int*)d_in[1];
    float* new_out = (float*)d_out;                      // 8192*100 floats
    float* new_lab = (float*)d_out + (size_t)NROWS * K;  // 8192 floats

    logit_selector_kernel<<<dim3(NROWS), dim3(BLK), 0, stream>>>(
        out_mat, labels, new_out, new_lab);
}

// Round 6
// 305.958 us; speedup vs baseline: 1.1437x; 1.1437x over previous
//
#include <hip/hip_runtime.h>

// LogitSelector: per-row top-100 (ascending), label position, miss→replace col 0.
// Reference: jax.lax.top_k (ties: lower index first), reversed; take_along_axis; argmax.
//
// R6: register-resident row (14 float2/thread, full MLP, retries free);
// speculative threshold t=2.1 (C~120, retry ladder 1.85 -> bisection);
// rank via 32-bit flipped keys + readlane broadcast (5 VALU/candidate),
// exact-tie detection (self-inclusive eq count >= 2) -> rare 64-bit slow path;
// fully-inactive waves skip the rank loop.

#define NROWS 8192
#define NCOLS 6714
#define NC2   3357     // NCOLS/2; rows are 8B-aligned (26856 % 8 == 0)
#define K     100
#define CAP   512
#define BLK   256
#define VPT   14       // ceil(NC2/BLK); threads tid<29 own 14 float2, rest 13

__device__ __forceinline__ unsigned int flip32(float v) {
    unsigned int b = __float_as_uint(v);
    return ((int)b < 0) ? ~b : (b | 0x80000000u);   // order-preserving
}
__device__ __forceinline__ float unflip32(unsigned int k) {
    return __uint_as_float((k & 0x80000000u) ? (k ^ 0x80000000u) : ~k);
}

__global__ __launch_bounds__(BLK) void logit_selector_kernel(
    const float* __restrict__ out_mat,
    const int*   __restrict__ labels,
    float*       __restrict__ new_out,   // [NROWS][K]
    float*       __restrict__ new_lab)   // [NROWS] written as float
{
    __shared__ unsigned int cvkey[CAP];   // 2 KB
    __shared__ unsigned int cidx[CAP];    // 2 KB
    __shared__ unsigned int s_cnum;
    __shared__ int s_lab, s_has, s_dup;

    const int row  = blockIdx.x;
    const int tid  = threadIdx.x;
    const int lane = tid & 63;
    const float2* __restrict__ rp2 = (const float2*)(out_mat + (size_t)row * NCOLS);

    // --- Register-resident row slice: all loads issued back-to-back (MLP).
    float2 v[VPT];
    #pragma unroll
    for (int k = 0; k < VPT - 1; ++k) v[k] = rp2[tid + k * BLK];
    const bool hasLast = (tid + (VPT - 1) * BLK) < NC2;   // tid < 29
    v[VPT - 1] = hasLast ? rp2[tid + (VPT - 1) * BLK] : make_float2(-1e30f, -1e30f);

    if (tid == 0) { s_has = 0; s_lab = 0; s_dup = 0; }

    // --- Candidate collection: speculative threshold, retries scan registers.
    float lo = -400.0f, hi = 400.0f, t = 2.1f;
    unsigned int cnt;
    for (int attempt = 0; ; ++attempt) {
        if (tid == 0) s_cnum = 0;
        __syncthreads();
        #pragma unroll
        for (int k = 0; k < VPT; ++k) {
            if (v[k].x > t) {
                unsigned int p = atomicAdd(&s_cnum, 1u);
                if (p < CAP) { cvkey[p] = flip32(v[k].x); cidx[p] = 2*(tid + k*BLK); }
            }
            if (v[k].y > t) {
                unsigned int p = atomicAdd(&s_cnum, 1u);
                if (p < CAP) { cvkey[p] = flip32(v[k].y); cidx[p] = 2*(tid + k*BLK) + 1; }
            }
        }
        __syncthreads();
        cnt = s_cnum;                        // uniform across block
        if ((cnt >= K && cnt <= CAP) || attempt >= 62) break;
        if (cnt < (unsigned int)K) hi = t; else lo = t;
        t = (attempt == 0) ? ((cnt < (unsigned int)K) ? 1.85f : 2.35f)
                           : 0.5f * (lo + hi);
        __syncthreads();                     // protect next reset vs. cnt reads
    }

    const int C    = (int)min(cnt, (unsigned int)CAP);
    const int Cpad = (C + 63) & ~63;
    for (int c = C + tid; c < Cpad; c += BLK) { cvkey[c] = 0u; cidx[c] = 0xFFFFFFFFu; }
    __syncthreads();

    const int label = labels[row];

    // --- Fast rank: 32-bit value keys; detect exact fp32 ties for slow path.
    // rank(j) = #{c: key_c > key_j}. Distinct keys -> bijective onto [0,C).
    // rank k < K -> column (K-1)-k (reference reverses top_k order).
    for (int jbase = 0; jbase < C; jbase += BLK) {
        const int  j      = jbase + tid;
        const bool active = (j < C);
        if (__ballot(active) == 0) continue;          // whole wave idle
        unsigned int kj = 0;
        if (active) kj = cvkey[j];
        int rank = 0, eqc = 0;
        for (int cb = 0; cb < Cpad; cb += 64) {
            const unsigned int kt = cvkey[cb + lane];  // all lanes execute
            #pragma unroll
            for (int l = 0; l < 64; ++l) {
                const unsigned int kc = __builtin_amdgcn_readlane(kt, l);
                rank += (kc > kj);
                eqc  += (kc == kj);                    // includes self once
            }
        }
        if (active) {
            if (eqc >= 2) s_dup = 1;                   // exact value tie in row
            if (rank < K) {
                const int col = (K - 1) - rank;
                new_out[(size_t)row * K + col] = unflip32(kj);
                if ((int)cidx[j] == label) { s_has = 1; s_lab = col; }
            }
        }
    }
    __syncthreads();

    // --- Slow path (rare, ~1 row per batch): exact (value desc, index asc).
    if (s_dup) {
        if (tid == 0) { s_has = 0; s_lab = 0; }
        __syncthreads();
        for (int jbase = 0; jbase < C; jbase += BLK) {
            const int  j      = jbase + tid;
            const bool active = (j < C);
            if (__ballot(active) == 0) continue;
            unsigned int kj = 0, ijx = 0xFFFFFFFFu;
            if (active) { kj = cvkey[j]; ijx = cidx[j]; }
            int rank = 0;
            for (int cb = 0; cb < Cpad; cb += 64) {
                const unsigned int kt = cvkey[cb + lane];
                const unsigned int it = cidx[cb + lane];
                #pragma unroll
                for (int l = 0; l < 64; ++l) {
                    const unsigned int kc = __builtin_amdgcn_readlane(kt, l);
                    const unsigned int ic = __builtin_amdgcn_readlane(it, l);
                    rank += (kc > kj) || (kc == kj && ic < ijx);
                }
            }
            if (active && rank < K) {                  // bijective: all K written
                const int col = (K - 1) - rank;
                new_out[(size_t)row * K + col] = unflip32(kj);
                if ((int)cidx[j] == label) { s_has = 1; s_lab = col; }
            }
        }
        __syncthreads();
    }

    if (tid == 0) {
        int lab = s_lab;
        if (!s_has) {                        // label missed top-K: replace col 0
            const float* rp = out_mat + (size_t)row * NCOLS;
            new_out[(size_t)row * K] = rp[label];
            lab = 0;
        }
        new_lab[row] = (float)lab;
    }
}

extern "C" void kernel_launch(void* const* d_in, const int* in_sizes, int n_in,
                              void* d_out, int out_size, void* d_ws, size_t ws_size,
                              hipStream_t stream) {
    const float* out_mat = (const float*)d_in[0];
    const int*   labels  = (const int*)d_in[1];
    float* new_out = (float*)d_out;                      // 8192*100 floats
    float* new_lab = (float*)d_out + (size_t)NROWS * K;  // 8192 floats

    logit_selector_kernel<<<dim3(NROWS), dim3(BLK), 0, stream>>>(
        out_mat, labels, new_out, new_lab);
}